// Round 3
// baseline (598.045 us; speedup 1.0000x reference)
//
#include <hip/hip_runtime.h>
#include <hip/hip_bf16.h>

using bf16x8 = __attribute__((ext_vector_type(8))) short;
using f32x4  = __attribute__((ext_vector_type(4))) float;
typedef unsigned short u16;

__device__ __forceinline__ u16 f2bf(float f) {
  unsigned int u = __float_as_uint(f);
  u += 0x7FFFu + ((u >> 16) & 1u);
  return (u16)(u >> 16);
}

__device__ __forceinline__ f32x4 mfma16(bf16x8 a, bf16x8 b, f32x4 c) {
  return __builtin_amdgcn_mfma_f32_16x16x32_bf16(a, b, c, 0, 0, 0);
}

// ---------------------------------------------------------------------------
// fp32 -> bf16 converts (memory-bound)
// ---------------------------------------------------------------------------
__global__ __launch_bounds__(256) void cvt_kernel(
    const float* __restrict__ src, u16* __restrict__ dst) {
  const int i = (blockIdx.x * 256 + threadIdx.x) * 8;
  float4 v0 = *reinterpret_cast<const float4*>(src + i);
  float4 v1 = *reinterpret_cast<const float4*>(src + i + 4);
  u16 o[8] = {f2bf(v0.x), f2bf(v0.y), f2bf(v0.z), f2bf(v0.w),
              f2bf(v1.x), f2bf(v1.y), f2bf(v1.z), f2bf(v1.w)};
  *reinterpret_cast<int4*>(dst + i) = *reinterpret_cast<int4*>(o);
}

__global__ __launch_bounds__(256) void cvtW_kernel(
    const float* __restrict__ w0, const float* __restrict__ w1,
    const float* __restrict__ w2, u16* __restrict__ dst) {
  const float* src = (blockIdx.y == 0) ? w0 : (blockIdx.y == 1) ? w1 : w2;
  u16* d = dst + (size_t)blockIdx.y * 1048576;
  const int i = (blockIdx.x * 256 + threadIdx.x) * 8;
  float4 v0 = *reinterpret_cast<const float4*>(src + i);
  float4 v1 = *reinterpret_cast<const float4*>(src + i + 4);
  u16 o[8] = {f2bf(v0.x), f2bf(v0.y), f2bf(v0.z), f2bf(v0.w),
              f2bf(v1.x), f2bf(v1.y), f2bf(v1.z), f2bf(v1.w)};
  *reinterpret_cast<int4*>(d + i) = *reinterpret_cast<int4*>(o);
}

// ---------------------------------------------------------------------------
// Projection GEMM (bf16 in, bf16 out): Y = (X @ W^T + bias) * scale
// mat 0: Q (normal layout), 1: K (normal), 2: V (transposed per head:
//        Y[(b*1024 + n)*1024 + s])
// ---------------------------------------------------------------------------
__global__ __launch_bounds__(256) void proj_kernel(
    const u16* __restrict__ X, const u16* __restrict__ W,
    const float* __restrict__ Bi, u16* __restrict__ Y, int mat, float scale)
{
  __shared__ u16 As[128][40];   // 80 B stride: 16B-aligned, good bank spread
  __shared__ u16 Bs[128][40];

  const int tid  = threadIdx.x;
  const int lane = tid & 63;
  const int w    = tid >> 6;
  const int m0 = blockIdx.y * 128;
  const int n0 = blockIdx.x * 128;
  const int wm = (w >> 1) * 64;
  const int wn = (w & 1) * 64;
  const int fr = lane & 15;
  const int fg = lane >> 4;

  const int sr = tid >> 1;          // staging row 0..127
  const int sc = (tid & 1) * 16;    // staging col 0/16
  const u16* ap = X + (size_t)(m0 + sr) * 1024 + sc;
  const u16* bp = W + (size_t)(n0 + sr) * 1024 + sc;

  f32x4 zero = {0.f, 0.f, 0.f, 0.f};
  f32x4 acc[4][4];
#pragma unroll
  for (int i = 0; i < 4; i++)
#pragma unroll
    for (int j = 0; j < 4; j++) acc[i][j] = zero;

  for (int kk = 0; kk < 1024; kk += 32) {
    int4 ga0 = *reinterpret_cast<const int4*>(ap + kk);
    int4 ga1 = *reinterpret_cast<const int4*>(ap + kk + 8);
    int4 gb0 = *reinterpret_cast<const int4*>(bp + kk);
    int4 gb1 = *reinterpret_cast<const int4*>(bp + kk + 8);

    __syncthreads();  // previous iteration's fragment reads complete
    *reinterpret_cast<int4*>(&As[sr][sc + 0]) = ga0;
    *reinterpret_cast<int4*>(&As[sr][sc + 8]) = ga1;
    *reinterpret_cast<int4*>(&Bs[sr][sc + 0]) = gb0;
    *reinterpret_cast<int4*>(&Bs[sr][sc + 8]) = gb1;
    __syncthreads();

    bf16x8 af[4], bff[4];
#pragma unroll
    for (int i = 0; i < 4; i++) {
      af[i]  = *reinterpret_cast<const bf16x8*>(&As[wm + i*16 + fr][fg*8]);
      bff[i] = *reinterpret_cast<const bf16x8*>(&Bs[wn + i*16 + fr][fg*8]);
    }
#pragma unroll
    for (int i = 0; i < 4; i++)
#pragma unroll
      for (int j = 0; j < 4; j++)
        acc[i][j] = mfma16(af[i], bff[j], acc[i][j]);
  }

  // epilogue: C/D layout row=(lane>>4)*4+reg, col=lane&15
#pragma unroll
  for (int j = 0; j < 4; j++) {
    const int n = n0 + wn + j*16 + fr;
    const float bias = Bi[n];
#pragma unroll
    for (int i = 0; i < 4; i++) {
      const int mbase = m0 + wm + i*16 + fg*4;
      if (mat == 2) {
        u16 pk[4];
#pragma unroll
        for (int r = 0; r < 4; r++) pk[r] = f2bf((acc[i][j][r] + bias) * scale);
        const int bidx = mbase >> 10;
        const int s = mbase & 1023;
        *reinterpret_cast<uint2*>(&Y[((size_t)(bidx * 1024 + n)) * 1024 + s]) =
            *reinterpret_cast<uint2*>(pk);
      } else {
#pragma unroll
        for (int r = 0; r < 4; r++) {
          Y[(size_t)(mbase + r) * 1024 + n] = f2bf((acc[i][j][r] + bias) * scale);
        }
      }
    }
  }
}

// ---------------------------------------------------------------------------
// Attention output kernel. grid (qt=16, h=16, b=8), 256 threads (4 waves).
// Wave w handles q rows [qt*64 + w*16, +16). NO barriers: K and V fragments
// are read directly from global (L1/L2-resident), only the per-wave Tl
// relayout tile uses LDS (same-wave write->read, compiler orders lgkmcnt).
// Pass 1: Z = sum_k exp(s - 8)  (fixed shift; scores are O(1) in fp32)
// Pass 2: t = tanh(exp(s-8)/Z), O += t @ V. Writes attn_output and rcpZ.
// ---------------------------------------------------------------------------
__global__ __launch_bounds__(256) void attn_out_kernel(
    const u16* __restrict__ Qbf, const u16* __restrict__ Kbf, const u16* __restrict__ Vt,
    float* __restrict__ outA, float* __restrict__ rcpZ)
{
  const int qt = blockIdx.x;
  const int h  = blockIdx.y;
  const int b  = blockIdx.z;
  const int tid  = threadIdx.x;
  const int lane = tid & 63;
  const int w    = tid >> 6;
  const int fr = lane & 15;
  const int fg = lane >> 4;

  __shared__ u16 Tl[4][16][40];  // per-wave t relayout buffer

  const int qbase = qt * 64 + w * 16;

  // Q fragments (registers), Q pre-scaled by 1/8 at projection time
  const u16* qp = Qbf + ((size_t)(b * 1024 + qbase + fr)) * 1024 + h * 64 + fg * 8;
  const bf16x8 qf0 = *reinterpret_cast<const bf16x8*>(qp);
  const bf16x8 qf1 = *reinterpret_cast<const bf16x8*>(qp + 32);

  // K fragment base: row fr (+16 for second frag), col h*64 + fg*8 (+32)
  const u16* kb = Kbf + ((size_t)(b * 1024 + fr)) * 1024 + h * 64 + fg * 8;
  // V fragment base (Vt is [B,H,64,S]): row e*16+fr, col kt*32 + fg*8
  const u16* vb = Vt + ((size_t)((b * 16 + h) * 64 + fr)) * 1024 + fg * 8;

  f32x4 zero = {0.f, 0.f, 0.f, 0.f};
  float zacc[4] = {0.f, 0.f, 0.f, 0.f};

  // ---------------- pass 1: Z ----------------
  for (int kt = 0; kt < 32; kt++) {
    const u16* kr = kb + (size_t)(kt * 32) * 1024;
    bf16x8 k0a = *reinterpret_cast<const bf16x8*>(kr);
    bf16x8 k0b = *reinterpret_cast<const bf16x8*>(kr + 32);
    bf16x8 k1a = *reinterpret_cast<const bf16x8*>(kr + 16 * 1024);
    bf16x8 k1b = *reinterpret_cast<const bf16x8*>(kr + 16 * 1024 + 32);
    f32x4 s0 = zero, s1 = zero;
    s0 = mfma16(qf0, k0a, s0); s0 = mfma16(qf1, k0b, s0);
    s1 = mfma16(qf0, k1a, s1); s1 = mfma16(qf1, k1b, s1);
#pragma unroll
    for (int r = 0; r < 4; r++)
      zacc[r] += __expf(s0[r] - 8.f) + __expf(s1[r] - 8.f);
  }
#pragma unroll
  for (int r = 0; r < 4; r++) {
    float z = zacc[r];
    z += __shfl_xor(z, 1); z += __shfl_xor(z, 2);
    z += __shfl_xor(z, 4); z += __shfl_xor(z, 8);
    zacc[r] = z;
  }
  float rz[4];
#pragma unroll
  for (int r = 0; r < 4; r++) rz[r] = 1.0f / zacc[r];
  if (fr == 0) {
#pragma unroll
    for (int r = 0; r < 4; r++)
      rcpZ[((size_t)(b * 16 + h)) * 1024 + qbase + fg * 4 + r] = rz[r];
  }

  // ---------------- pass 2: O = tanh(p) @ V ----------------
  f32x4 o[4];
#pragma unroll
  for (int e = 0; e < 4; e++) o[e] = zero;

  for (int kt = 0; kt < 32; kt++) {
    const u16* kr = kb + (size_t)(kt * 32) * 1024;
    bf16x8 k0a = *reinterpret_cast<const bf16x8*>(kr);
    bf16x8 k0b = *reinterpret_cast<const bf16x8*>(kr + 32);
    bf16x8 k1a = *reinterpret_cast<const bf16x8*>(kr + 16 * 1024);
    bf16x8 k1b = *reinterpret_cast<const bf16x8*>(kr + 16 * 1024 + 32);
    bf16x8 bv[4];
#pragma unroll
    for (int e = 0; e < 4; e++)
      bv[e] = *reinterpret_cast<const bf16x8*>(vb + (size_t)(e * 16) * 1024 + kt * 32);

    f32x4 s0 = zero, s1 = zero;
    s0 = mfma16(qf0, k0a, s0); s0 = mfma16(qf1, k0b, s0);
    s1 = mfma16(qf0, k1a, s1); s1 = mfma16(qf1, k1b, s1);

    // t = tanh(p), stored into per-wave LDS tile in D-layout
#pragma unroll
    for (int r = 0; r < 4; r++) {
      float p0 = __expf(s0[r] - 8.f) * rz[r];
      float p1 = __expf(s1[r] - 8.f) * rz[r];
      float u0 = __expf(-2.f * p0);
      float u1 = __expf(-2.f * p1);
      float t0 = __fdividef(1.f - u0, 1.f + u0);
      float t1 = __fdividef(1.f - u1, 1.f + u1);
      Tl[w][fg*4 + r][fr]      = f2bf(t0);
      Tl[w][fg*4 + r][16 + fr] = f2bf(t1);
    }
    // re-read in A-fragment layout (same wave; lgkmcnt ordering by compiler)
    bf16x8 af = *reinterpret_cast<const bf16x8*>(&Tl[w][fr][fg*8]);
#pragma unroll
    for (int e = 0; e < 4; e++) o[e] = mfma16(af, bv[e], o[e]);
  }

#pragma unroll
  for (int e = 0; e < 4; e++)
#pragma unroll
    for (int r = 0; r < 4; r++)
      outA[((size_t)(b * 1024 + qbase + fg*4 + r)) * 1024 + h * 64 + e*16 + fr] = o[e][r];
}

// ---------------------------------------------------------------------------
// Weights kernel: outW[b,q,k] = mean_h tanh(exp(s-8)*rcpZ).
// grid (qt=32, ks=2, b=8) = 512 blocks, 512 threads (8 waves).
// Wave w owns output frag (qi=w>>2, ki=w&3); K fragments read DIRECTLY from
// global (no LDS staging, no barriers in the loop). h outer / kt inner with
// wsum[8] register accumulators -> 8 independent chains for latency hiding.
// ---------------------------------------------------------------------------
__global__ __launch_bounds__(512) void attn_w_kernel(
    const u16* __restrict__ Qbf, const u16* __restrict__ Kbf,
    const float* __restrict__ rcpZ, float* __restrict__ outW)
{
  const int qt = blockIdx.x;
  const int ks = blockIdx.y;
  const int b  = blockIdx.z;
  const int tid  = threadIdx.x;
  const int lane = tid & 63;
  const int w    = tid >> 6;
  const int qi = w >> 2;   // 0..1
  const int ki = w & 3;    // 0..3
  const int fr = lane & 15;
  const int fg = lane >> 4;

  __shared__ u16 Qall[32][1032];     // 2064 B stride
  __shared__ float statsL[16][32];   // [h][row]

  {
    const int qrow = tid >> 4;            // 0..31
    const int qoffb = (tid & 15) * 64;
    const u16* qsrc = Qbf + ((size_t)(b * 1024 + qt * 32 + qrow)) * 1024 + qoffb;
#pragma unroll
    for (int i = 0; i < 8; i++)
      *reinterpret_cast<int4*>(&Qall[qrow][qoffb + i*8]) =
          *reinterpret_cast<const int4*>(qsrc + i*8);
    const int hh = tid >> 5, rr = tid & 31;
    statsL[hh][rr] = rcpZ[((size_t)(b * 16 + hh)) * 1024 + qt * 32 + rr];
  }
  __syncthreads();

  const u16* kbase = Kbf + ((size_t)(b * 1024 + ks * 512 + ki * 16 + fr)) * 1024 + fg * 8;

  f32x4 wsum[8];
#pragma unroll
  for (int kt = 0; kt < 8; kt++) wsum[kt] = f32x4{0.f, 0.f, 0.f, 0.f};

  for (int h = 0; h < 16; h++) {
    bf16x8 a0 = *reinterpret_cast<const bf16x8*>(&Qall[qi*16 + fr][h*64 + fg*8]);
    bf16x8 a1 = *reinterpret_cast<const bf16x8*>(&Qall[qi*16 + fr][h*64 + 32 + fg*8]);
    float rza[4];
#pragma unroll
    for (int r = 0; r < 4; r++) rza[r] = statsL[h][qi*16 + fg*4 + r];

#pragma unroll 4
    for (int kt = 0; kt < 8; kt++) {
      bf16x8 b0 = *reinterpret_cast<const bf16x8*>(kbase + (size_t)kt * 65536 + h * 64);
      bf16x8 b1 = *reinterpret_cast<const bf16x8*>(kbase + (size_t)kt * 65536 + h * 64 + 32);
      f32x4 s = {0.f, 0.f, 0.f, 0.f};
      s = mfma16(a0, b0, s);
      s = mfma16(a1, b1, s);
#pragma unroll
      for (int r = 0; r < 4; r++) {
        float p = __expf(s[r] - 8.f) * rza[r];
        float u = __expf(-2.f * p);
        wsum[kt][r] += __fdividef(1.f - u, 1.f + u);
      }
    }
  }

#pragma unroll
  for (int kt = 0; kt < 8; kt++)
#pragma unroll
    for (int r = 0; r < 4; r++)
      outW[((size_t)(b*1024 + qt*32 + qi*16 + fg*4 + r)) * 1024 + ks*512 + kt*64 + ki*16 + fr] =
          wsum[kt][r] * 0.0625f;
}

// ---------------------------------------------------------------------------
extern "C" void kernel_launch(void* const* d_in, const int* in_sizes, int n_in,
                              void* d_out, int out_size, void* d_ws, size_t ws_size,
                              hipStream_t stream) {
  const float* query = (const float*)d_in[0];
  const float* key_  = (const float*)d_in[1];
  const float* value = (const float*)d_in[2];
  const float* Wq = (const float*)d_in[3];
  const float* bq = (const float*)d_in[4];
  const float* Wk = (const float*)d_in[5];
  const float* bk = (const float*)d_in[6];
  const float* Wv = (const float*)d_in[7];
  const float* bv = (const float*)d_in[8];

  float* outA = (float*)d_out;            // [8,1024,1024]
  float* outW = outA + 8388608;           // [8,1024,1024]

  u16* Qbf = (u16*)d_ws;                  // bf16, Q pre-scaled by 1/8
  u16* Kbf = Qbf + 8388608;
  u16* Vt  = Kbf + 8388608;               // [B,H,64,S] transposed per head
  u16* Xbf = Vt + 8388608;                // 16.8MB reusable input slot
  u16* Wbf = Xbf + 8388608;               // 3 x 1M bf16 weights
  float* rcpZ = (float*)(Wbf + 3145728);  // [B,H,S]

  cvtW_kernel<<<dim3(512, 3), 256, 0, stream>>>(Wq, Wk, Wv, Wbf);

  cvt_kernel<<<4096, 256, 0, stream>>>(query, Xbf);
  proj_kernel<<<dim3(8, 64), 256, 0, stream>>>(Xbf, Wbf, bq, Qbf, 0, 0.125f);

  cvt_kernel<<<4096, 256, 0, stream>>>(key_, Xbf);
  proj_kernel<<<dim3(8, 64), 256, 0, stream>>>(Xbf, Wbf + 1048576, bk, Kbf, 1, 1.0f);

  cvt_kernel<<<4096, 256, 0, stream>>>(value, Xbf);
  proj_kernel<<<dim3(8, 64), 256, 0, stream>>>(Xbf, Wbf + 2097152, bv, Vt, 2, 1.0f);

  attn_out_kernel<<<dim3(16, 16, 8), 256, 0, stream>>>(Qbf, Kbf, Vt, outA, rcpZ);
  attn_w_kernel<<<dim3(32, 2, 8), 512, 0, stream>>>(Qbf, Kbf, rcpZ, outW);
}

// Round 4
// 502.732 us; speedup vs baseline: 1.1896x; 1.1896x over previous
//
#include <hip/hip_runtime.h>
#include <hip/hip_bf16.h>

using bf16x8 = __attribute__((ext_vector_type(8))) short;
using f32x4  = __attribute__((ext_vector_type(4))) float;
typedef unsigned short u16;

__device__ __forceinline__ u16 f2bf(float f) {
  unsigned int u = __float_as_uint(f);
  u += 0x7FFFu + ((u >> 16) & 1u);
  return (u16)(u >> 16);
}

__device__ __forceinline__ float bf2f(u16 b) {
  return __uint_as_float(((unsigned int)b) << 16);
}

__device__ __forceinline__ f32x4 mfma16(bf16x8 a, bf16x8 b, f32x4 c) {
  return __builtin_amdgcn_mfma_f32_16x16x32_bf16(a, b, c, 0, 0, 0);
}

// ---------------------------------------------------------------------------
// fp32 -> bf16 converts (memory-bound)
// ---------------------------------------------------------------------------
__global__ __launch_bounds__(256) void cvt_kernel(
    const float* __restrict__ src, u16* __restrict__ dst) {
  const int i = (blockIdx.x * 256 + threadIdx.x) * 8;
  float4 v0 = *reinterpret_cast<const float4*>(src + i);
  float4 v1 = *reinterpret_cast<const float4*>(src + i + 4);
  u16 o[8] = {f2bf(v0.x), f2bf(v0.y), f2bf(v0.z), f2bf(v0.w),
              f2bf(v1.x), f2bf(v1.y), f2bf(v1.z), f2bf(v1.w)};
  *reinterpret_cast<int4*>(dst + i) = *reinterpret_cast<int4*>(o);
}

__global__ __launch_bounds__(256) void cvtW_kernel(
    const float* __restrict__ w0, const float* __restrict__ w1,
    const float* __restrict__ w2, u16* __restrict__ dst) {
  const float* src = (blockIdx.y == 0) ? w0 : (blockIdx.y == 1) ? w1 : w2;
  u16* d = dst + (size_t)blockIdx.y * 1048576;
  const int i = (blockIdx.x * 256 + threadIdx.x) * 8;
  float4 v0 = *reinterpret_cast<const float4*>(src + i);
  float4 v1 = *reinterpret_cast<const float4*>(src + i + 4);
  u16 o[8] = {f2bf(v0.x), f2bf(v0.y), f2bf(v0.z), f2bf(v0.w),
              f2bf(v1.x), f2bf(v1.y), f2bf(v1.z), f2bf(v1.w)};
  *reinterpret_cast<int4*>(d + i) = *reinterpret_cast<int4*>(o);
}

// ---------------------------------------------------------------------------
// Projection GEMM (bf16 in, bf16 out): Y = (X @ W^T + bias) * scale
// mat 0: Q (normal layout), 1: K (normal), 2: V (transposed per head:
//        Y[(b*1024 + n)*1024 + s])
// ---------------------------------------------------------------------------
__global__ __launch_bounds__(256) void proj_kernel(
    const u16* __restrict__ X, const u16* __restrict__ W,
    const float* __restrict__ Bi, u16* __restrict__ Y, int mat, float scale)
{
  __shared__ u16 As[128][40];   // 80 B stride: 16B-aligned, good bank spread
  __shared__ u16 Bs[128][40];

  const int tid  = threadIdx.x;
  const int lane = tid & 63;
  const int w    = tid >> 6;
  const int m0 = blockIdx.y * 128;
  const int n0 = blockIdx.x * 128;
  const int wm = (w >> 1) * 64;
  const int wn = (w & 1) * 64;
  const int fr = lane & 15;
  const int fg = lane >> 4;

  const int sr = tid >> 1;          // staging row 0..127
  const int sc = (tid & 1) * 16;    // staging col 0/16
  const u16* ap = X + (size_t)(m0 + sr) * 1024 + sc;
  const u16* bp = W + (size_t)(n0 + sr) * 1024 + sc;

  f32x4 zero = {0.f, 0.f, 0.f, 0.f};
  f32x4 acc[4][4];
#pragma unroll
  for (int i = 0; i < 4; i++)
#pragma unroll
    for (int j = 0; j < 4; j++) acc[i][j] = zero;

  for (int kk = 0; kk < 1024; kk += 32) {
    int4 ga0 = *reinterpret_cast<const int4*>(ap + kk);
    int4 ga1 = *reinterpret_cast<const int4*>(ap + kk + 8);
    int4 gb0 = *reinterpret_cast<const int4*>(bp + kk);
    int4 gb1 = *reinterpret_cast<const int4*>(bp + kk + 8);

    __syncthreads();  // previous iteration's fragment reads complete
    *reinterpret_cast<int4*>(&As[sr][sc + 0]) = ga0;
    *reinterpret_cast<int4*>(&As[sr][sc + 8]) = ga1;
    *reinterpret_cast<int4*>(&Bs[sr][sc + 0]) = gb0;
    *reinterpret_cast<int4*>(&Bs[sr][sc + 8]) = gb1;
    __syncthreads();

    bf16x8 af[4], bff[4];
#pragma unroll
    for (int i = 0; i < 4; i++) {
      af[i]  = *reinterpret_cast<const bf16x8*>(&As[wm + i*16 + fr][fg*8]);
      bff[i] = *reinterpret_cast<const bf16x8*>(&Bs[wn + i*16 + fr][fg*8]);
    }
#pragma unroll
    for (int i = 0; i < 4; i++)
#pragma unroll
      for (int j = 0; j < 4; j++)
        acc[i][j] = mfma16(af[i], bff[j], acc[i][j]);
  }

  // epilogue: C/D layout row=(lane>>4)*4+reg, col=lane&15
#pragma unroll
  for (int j = 0; j < 4; j++) {
    const int n = n0 + wn + j*16 + fr;
    const float bias = Bi[n];
#pragma unroll
    for (int i = 0; i < 4; i++) {
      const int mbase = m0 + wm + i*16 + fg*4;
      if (mat == 2) {
        u16 pk[4];
#pragma unroll
        for (int r = 0; r < 4; r++) pk[r] = f2bf((acc[i][j][r] + bias) * scale);
        const int bidx = mbase >> 10;
        const int s = mbase & 1023;
        *reinterpret_cast<uint2*>(&Y[((size_t)(bidx * 1024 + n)) * 1024 + s]) =
            *reinterpret_cast<uint2*>(pk);
      } else {
#pragma unroll
        for (int r = 0; r < 4; r++) {
          Y[(size_t)(mbase + r) * 1024 + n] = f2bf((acc[i][j][r] + bias) * scale);
        }
      }
    }
  }
}

// ---------------------------------------------------------------------------
// Attention output kernel. 2048 blocks, 512 threads (8 waves).
// Block decode (XCD-locality): xcd = bid&7; all 16 q-tile blocks of a given
// (b,h) land on the same XCD so its 256KB K/V slice stays L2-resident.
// Wave w = (qg = w&3, kh = w>>2): q rows [qt*64+qg*16, +16), k half kh*512.
// Pass A: single QK^T; E = exp(s-8) stored bf16 in wave-private LDS rows
//         (D-layout write / A-layout read does the transpose for free; no
//         barriers needed for Sc). Z combined across kh pairs via zpart.
// Pass B: t = tanh(E*rz) from LDS, PV-MFMA vs global V (L2-hot), O partials
//         combined via Ored. Only 2 barriers total per block.
// ---------------------------------------------------------------------------
__global__ __launch_bounds__(512) void attn_out_kernel(
    const u16* __restrict__ Qbf, const u16* __restrict__ Kbf, const u16* __restrict__ Vt,
    float* __restrict__ outA, float* __restrict__ rcpZ)
{
  __shared__ u16 Sc[4][16][1032];    // 132096 B, E values, wave-pair rows
  __shared__ float zpart[2][4][16];  // 512 B
  __shared__ float Ored[4][16][68];  // 17408 B  (total 150016 <= 160K)

  const int bid = blockIdx.x;
  const int xcd = bid & 7;
  const int wi  = bid >> 3;
  const int qt  = wi & 15;
  const int bh  = ((wi >> 4) << 3) | xcd;  // 0..127, same-bh -> same XCD
  const int b   = bh >> 4;
  const int h   = bh & 15;

  const int tid  = threadIdx.x;
  const int lane = tid & 63;
  const int w    = tid >> 6;
  const int qg = w & 3;    // q sub-tile
  const int kh = w >> 2;   // k half
  const int fr = lane & 15;
  const int fg = lane >> 4;

  const int qbase = qt * 64 + qg * 16;

  // Q fragments (Q pre-scaled by 1/8 at projection time)
  const u16* qp = Qbf + ((size_t)(b * 1024 + qbase + fr)) * 1024 + h * 64 + fg * 8;
  const bf16x8 qf0 = *reinterpret_cast<const bf16x8*>(qp);
  const bf16x8 qf1 = *reinterpret_cast<const bf16x8*>(qp + 32);

  // K fragment base: rows kh*512 + kt*32 + fr (+16), cols h*64 + fg*8 (+32)
  const u16* kb = Kbf + ((size_t)(b * 1024 + kh * 512 + fr)) * 1024 + h * 64 + fg * 8;
  // V fragment base (Vt is [B,H,64,S]): row e*16+fr, col kh*512 + kt*32 + fg*8
  const u16* vb = Vt + ((size_t)((b * 16 + h) * 64 + fr)) * 1024 + fg * 8;

  f32x4 zero = {0.f, 0.f, 0.f, 0.f};
  float zacc[4] = {0.f, 0.f, 0.f, 0.f};

  // ---------------- pass A: QK^T once, E -> LDS, Z partial ----------------
#pragma unroll 2
  for (int kt = 0; kt < 16; kt++) {
    const u16* kr = kb + (size_t)(kt * 32) * 1024;
    bf16x8 k0a = *reinterpret_cast<const bf16x8*>(kr);
    bf16x8 k0b = *reinterpret_cast<const bf16x8*>(kr + 32);
    bf16x8 k1a = *reinterpret_cast<const bf16x8*>(kr + 16 * 1024);
    bf16x8 k1b = *reinterpret_cast<const bf16x8*>(kr + 16 * 1024 + 32);
    f32x4 s0 = zero, s1 = zero;
    s0 = mfma16(qf0, k0a, s0); s0 = mfma16(qf1, k0b, s0);
    s1 = mfma16(qf0, k1a, s1); s1 = mfma16(qf1, k1b, s1);
#pragma unroll
    for (int r = 0; r < 4; r++) {
      float e0 = __expf(s0[r] - 8.f);
      float e1 = __expf(s1[r] - 8.f);
      zacc[r] += e0 + e1;
      u16* scr = &Sc[qg][fg*4 + r][kh*512 + kt*32];
      scr[fr]      = f2bf(e0);
      scr[16 + fr] = f2bf(e1);
    }
  }
  // reduce Z over fr lanes (cols of the score frags)
#pragma unroll
  for (int r = 0; r < 4; r++) {
    float z = zacc[r];
    z += __shfl_xor(z, 1); z += __shfl_xor(z, 2);
    z += __shfl_xor(z, 4); z += __shfl_xor(z, 8);
    zacc[r] = z;
  }
  if (fr == 0) {
#pragma unroll
    for (int r = 0; r < 4; r++) zpart[kh][qg][fg*4 + r] = zacc[r];
  }
  __syncthreads();

  const float rzv = 1.0f / (zpart[0][qg][fr] + zpart[1][qg][fr]);  // row q = fr
  if (kh == 0 && fg == 0)
    rcpZ[((size_t)(b * 16 + h)) * 1024 + qbase + fr] = rzv;

  // ---------------- pass B: t = tanh(E*rz), O += t @ V ----------------
  f32x4 o[4];
#pragma unroll
  for (int e = 0; e < 4; e++) o[e] = zero;

#pragma unroll 2
  for (int kt = 0; kt < 16; kt++) {
    bf16x8 eraw = *reinterpret_cast<const bf16x8*>(&Sc[qg][fr][kh*512 + kt*32 + fg*8]);
    bf16x8 bv[4];
#pragma unroll
    for (int e = 0; e < 4; e++)
      bv[e] = *reinterpret_cast<const bf16x8*>(
          vb + (size_t)(e * 16) * 1024 + kh * 512 + kt * 32);

    u16 tt[8];
#pragma unroll
    for (int j = 0; j < 8; j++) {
      float p = bf2f((u16)eraw[j]) * rzv;
      float u = __expf(-2.f * p);
      tt[j] = f2bf(__fdividef(1.f - u, 1.f + u));
    }
    bf16x8 af = *reinterpret_cast<const bf16x8*>(tt);
#pragma unroll
    for (int e = 0; e < 4; e++) o[e] = mfma16(af, bv[e], o[e]);
  }

  // combine kh pair partials
  if (kh == 1) {
#pragma unroll
    for (int e = 0; e < 4; e++)
#pragma unroll
      for (int r = 0; r < 4; r++) Ored[qg][fg*4 + r][e*16 + fr] = o[e][r];
  }
  __syncthreads();
  if (kh == 0) {
#pragma unroll
    for (int e = 0; e < 4; e++)
#pragma unroll
      for (int r = 0; r < 4; r++) {
        float v = o[e][r] + Ored[qg][fg*4 + r][e*16 + fr];
        outA[((size_t)(b * 1024 + qbase + fg*4 + r)) * 1024 + h * 64 + e*16 + fr] = v;
      }
  }
}

// ---------------------------------------------------------------------------
// Weights kernel: outW[b,q,k] = mean_h tanh(exp(s-8)*rcpZ).
// grid (qt=32, ks=2, b=8) = 512 blocks, 512 threads (8 waves).
// Wave w owns output frag (qi=w>>2, ki=w&3); K fragments read DIRECTLY from
// global (no LDS staging, no barriers in the loop). h outer / kt inner with
// wsum[8] register accumulators -> 8 independent chains for latency hiding.
// ---------------------------------------------------------------------------
__global__ __launch_bounds__(512) void attn_w_kernel(
    const u16* __restrict__ Qbf, const u16* __restrict__ Kbf,
    const float* __restrict__ rcpZ, float* __restrict__ outW)
{
  const int qt = blockIdx.x;
  const int ks = blockIdx.y;
  const int b  = blockIdx.z;
  const int tid  = threadIdx.x;
  const int lane = tid & 63;
  const int w    = tid >> 6;
  const int qi = w >> 2;   // 0..1
  const int ki = w & 3;    // 0..3
  const int fr = lane & 15;
  const int fg = lane >> 4;

  __shared__ u16 Qall[32][1032];     // 2064 B stride
  __shared__ float statsL[16][32];   // [h][row]

  {
    const int qrow = tid >> 4;            // 0..31
    const int qoffb = (tid & 15) * 64;
    const u16* qsrc = Qbf + ((size_t)(b * 1024 + qt * 32 + qrow)) * 1024 + qoffb;
#pragma unroll
    for (int i = 0; i < 8; i++)
      *reinterpret_cast<int4*>(&Qall[qrow][qoffb + i*8]) =
          *reinterpret_cast<const int4*>(qsrc + i*8);
    const int hh = tid >> 5, rr = tid & 31;
    statsL[hh][rr] = rcpZ[((size_t)(b * 16 + hh)) * 1024 + qt * 32 + rr];
  }
  __syncthreads();

  const u16* kbase = Kbf + ((size_t)(b * 1024 + ks * 512 + ki * 16 + fr)) * 1024 + fg * 8;

  f32x4 wsum[8];
#pragma unroll
  for (int kt = 0; kt < 8; kt++) wsum[kt] = f32x4{0.f, 0.f, 0.f, 0.f};

  for (int h = 0; h < 16; h++) {
    bf16x8 a0 = *reinterpret_cast<const bf16x8*>(&Qall[qi*16 + fr][h*64 + fg*8]);
    bf16x8 a1 = *reinterpret_cast<const bf16x8*>(&Qall[qi*16 + fr][h*64 + 32 + fg*8]);
    float rza[4];
#pragma unroll
    for (int r = 0; r < 4; r++) rza[r] = statsL[h][qi*16 + fg*4 + r];

#pragma unroll 4
    for (int kt = 0; kt < 8; kt++) {
      bf16x8 b0 = *reinterpret_cast<const bf16x8*>(kbase + (size_t)kt * 65536 + h * 64);
      bf16x8 b1 = *reinterpret_cast<const bf16x8*>(kbase + (size_t)kt * 65536 + h * 64 + 32);
      f32x4 s = {0.f, 0.f, 0.f, 0.f};
      s = mfma16(a0, b0, s);
      s = mfma16(a1, b1, s);
#pragma unroll
      for (int r = 0; r < 4; r++) {
        float p = __expf(s[r] - 8.f) * rza[r];
        float u = __expf(-2.f * p);
        wsum[kt][r] += __fdividef(1.f - u, 1.f + u);
      }
    }
  }

#pragma unroll
  for (int kt = 0; kt < 8; kt++)
#pragma unroll
    for (int r = 0; r < 4; r++)
      outW[((size_t)(b*1024 + qt*32 + qi*16 + fg*4 + r)) * 1024 + ks*512 + kt*64 + ki*16 + fr] =
          wsum[kt][r] * 0.0625f;
}

// ---------------------------------------------------------------------------
extern "C" void kernel_launch(void* const* d_in, const int* in_sizes, int n_in,
                              void* d_out, int out_size, void* d_ws, size_t ws_size,
                              hipStream_t stream) {
  const float* query = (const float*)d_in[0];
  const float* key_  = (const float*)d_in[1];
  const float* value = (const float*)d_in[2];
  const float* Wq = (const float*)d_in[3];
  const float* bq = (const float*)d_in[4];
  const float* Wk = (const float*)d_in[5];
  const float* bk = (const float*)d_in[6];
  const float* Wv = (const float*)d_in[7];
  const float* bv = (const float*)d_in[8];

  float* outA = (float*)d_out;            // [8,1024,1024]
  float* outW = outA + 8388608;           // [8,1024,1024]

  u16* Qbf = (u16*)d_ws;                  // bf16, Q pre-scaled by 1/8
  u16* Kbf = Qbf + 8388608;
  u16* Vt  = Kbf + 8388608;               // [B,H,64,S] transposed per head
  u16* Xbf = Vt + 8388608;                // 16.8MB reusable input slot
  u16* Wbf = Xbf + 8388608;               // 3 x 1M bf16 weights
  float* rcpZ = (float*)(Wbf + 3145728);  // [B,H,S]

  cvtW_kernel<<<dim3(512, 3), 256, 0, stream>>>(Wq, Wk, Wv, Wbf);

  cvt_kernel<<<4096, 256, 0, stream>>>(query, Xbf);
  proj_kernel<<<dim3(8, 64), 256, 0, stream>>>(Xbf, Wbf, bq, Qbf, 0, 0.125f);

  cvt_kernel<<<4096, 256, 0, stream>>>(key_, Xbf);
  proj_kernel<<<dim3(8, 64), 256, 0, stream>>>(Xbf, Wbf + 1048576, bk, Kbf, 1, 1.0f);

  cvt_kernel<<<4096, 256, 0, stream>>>(value, Xbf);
  proj_kernel<<<dim3(8, 64), 256, 0, stream>>>(Xbf, Wbf + 2097152, bv, Vt, 2, 1.0f);

  attn_out_kernel<<<dim3(2048), dim3(512), 0, stream>>>(Qbf, Kbf, Vt, outA, rcpZ);
  attn_w_kernel<<<dim3(32, 2, 8), 512, 0, stream>>>(Qbf, Kbf, rcpZ, outW);
}